// Round 17
// baseline (182.249 us; speedup 1.0000x reference)
//
#include <hip/hip_runtime.h>
#include <hip/hip_bf16.h>

typedef unsigned short u16;
typedef unsigned int   u32;
typedef unsigned char  u8;
typedef __attribute__((ext_vector_type(8))) __bf16 bfrag;
typedef __attribute__((ext_vector_type(4))) float  f32x4;

#define DEV __device__ __forceinline__

DEV u16 f2bf(float f){
  union { float f; u32 u; } v; v.f = f;
  u32 u = v.u;
  u32 r = (u + 0x7fffu + ((u >> 16) & 1u)) >> 16;
  return (u16)r;
}
DEV float bf2f(u16 x){
  union { u32 u; float f; } v; v.u = ((u32)x) << 16;
  return v.f;
}
DEV void gload16(const void* g, void* l){
  __builtin_amdgcn_global_load_lds((const __attribute__((address_space(1))) void*)g,
                                   (__attribute__((address_space(3))) void*)l, 16, 0, 0);
}

// ============ merged prep: counts | pack wb | pack dwb | cvt x->bf16 (one dispatch) =======
__global__ void k_prep(const float* __restrict__ x, const void* __restrict__ mask,
                       const float* __restrict__ wq, const float* __restrict__ wk,
                       const float* __restrict__ wv, const float* __restrict__ dw,
                       u16* __restrict__ xb, u16* __restrict__ wb, u16* __restrict__ dwb,
                       int* __restrict__ counts){
  int gb = blockIdx.x, t = threadIdx.x;
  if (gb < 16){
    int b = gb;
    u32 h0 = *(const u32*)mask;
    int mode = (h0 == 0x3f800000u) ? 2 : (h0 == 1u) ? 1 : 0;
    int cnt = 0;
    if (mode == 0){
      const u8* p = (const u8*)mask + (size_t)b * 2048;
      for (int i = t; i < 2048; i += 256) cnt += (p[i] != 0);
    } else if (mode == 1){
      const int* p = (const int*)mask + (size_t)b * 2048;
      for (int i = t; i < 2048; i += 256) cnt += (p[i] != 0);
    } else {
      const float* p = (const float*)mask + (size_t)b * 2048;
      for (int i = t; i < 2048; i += 256) cnt += (p[i] != 0.0f);
    }
    __shared__ int red[256];
    red[t] = cnt; __syncthreads();
    for (int s = 128; s > 0; s >>= 1){ if (t < s) red[t] += red[t + s]; __syncthreads(); }
    if (t == 0){ int c = red[0]; if (c < 1) c = 1; if (c > 2048) c = 2048; counts[b] = c; }
  } else if (gb < 400){
    int c = (gb - 16) * 256 + t;
    int kb8 = c / 1536, n = c % 1536;
    const float* w = (n < 512) ? wq : (n < 1024) ? wk : wv;
    int nn = n & 511;
    union { u16 o[8]; uint4 v; } u;
    #pragma unroll
    for (int j = 0; j < 8; ++j) u.o[j] = f2bf(w[(size_t)(kb8 * 8 + j) * 512 + nn]);
    *(uint4*)(wb + (size_t)c * 8) = u.v;
  } else if (gb < 528){
    int c = (gb - 400) * 256 + t;
    int kb8 = c >> 9, nn = c & 511;
    union { u16 o[8]; uint4 v; } u;
    #pragma unroll
    for (int j = 0; j < 8; ++j) u.o[j] = f2bf(dw[(size_t)(kb8 * 8 + j) * 512 + nn]);
    *(uint4*)(dwb + (size_t)c * 8) = u.v;
  } else {
    int i = (gb - 528) * 256 + t;
    int stride = (gridDim.x - 528) * 256;
    for (; i < 2097152; i += stride){
      const float4* s = (const float4*)(x + (size_t)i * 8);
      float4 a = s[0], b = s[1];
      union { u16 o[8]; uint4 v; } u;
      u.o[0]=f2bf(a.x); u.o[1]=f2bf(a.y); u.o[2]=f2bf(a.z); u.o[3]=f2bf(a.w);
      u.o[4]=f2bf(b.x); u.o[5]=f2bf(b.y); u.o[6]=f2bf(b.z); u.o[7]=f2bf(b.w);
      *(uint4*)(xb + (size_t)i * 8) = u.v;
    }
  }
}

// ---------------- 128x(128*NBI) bf16 MFMA GEMM, K=512, proven 2-barrier body ----------------
// NBI=2 for QKV (wider tile: 64 MFMA/wave per barrier, ds_read:MFMA = 0.75); NBI=1 dense.
// + XCD-ownership swizzle (1D grid; xcd = id&7 owns contiguous bm range, bn fast within)
template<int MODE, int NBI>
__launch_bounds__(256, 2)
__global__ void k_gemm(const u16* __restrict__ A, const u16* __restrict__ Bp,
                       u16* __restrict__ q, u16* __restrict__ kk, u16* __restrict__ vv,
                       float* __restrict__ out, const float* __restrict__ bias,
                       int N, int nbn){
  __shared__ __align__(16) char sA[16384];        // [128 rows][64 k] bf16, slot-XOR swizzled
  __shared__ __align__(16) char sB[NBI * 16384];  // [NBI][8 kb8][128 col][8] bf16 linear
  const int tid = threadIdx.x;
  const int wid = tid >> 6, lane = tid & 63;
  int id = blockIdx.x;
  int per = gridDim.x >> 3;
  int lin = (id & 7) * per + (id >> 3);
  const int bm = lin / nbn;
  const int bn = lin - bm * nbn;
  const int wm = wid >> 1, wn = wid & 1;
  const int l15 = lane & 15, l4 = lane >> 4;

  f32x4 acc[NBI][4][4] = {};

  const char* Ab = (const char*)A;
  const char* Bb = (const char*)Bp;

  for (int kt = 0; kt < 8; ++kt){
    __syncthreads();
    #pragma unroll
    for (int t = 0; t < 4; ++t){
      int chunk = (wid * 4 + t) * 64 + lane;
      int row = chunk >> 3, slot = chunk & 7;
      const char* g = Ab + ((size_t)(bm * 128 + row) * 1024) + kt * 128 + ((slot ^ (row & 7)) << 4);
      gload16(g, sA + (wid * 4 + t) * 1024);
    }
    #pragma unroll
    for (int t = 0; t < 4 * NBI; ++t){
      int idx = wid * 4 * NBI + t;                 // 0..16*NBI-1
      int bi = idx >> 4, w16 = idx & 15;
      int kb8l = w16 >> 1, col = ((w16 & 1) << 6) + lane;
      const char* g = Bb + ((size_t)((kt * 8 + kb8l) * N + bn * 128 * NBI + bi * 128 + col) << 4);
      gload16(g, sB + idx * 1024);
    }
    __syncthreads();
    #pragma unroll
    for (int ks = 0; ks < 2; ++ks){
      bfrag af[4];
      #pragma unroll
      for (int mt = 0; mt < 4; ++mt){
        int row = wm * 64 + mt * 16 + l15;
        int slot = ks * 4 + l4;
        af[mt] = __builtin_bit_cast(bfrag, *(const uint4*)(sA + row * 128 + ((slot << 4) ^ ((row & 7) << 4))));
      }
      #pragma unroll
      for (int bi = 0; bi < NBI; ++bi){
        bfrag bfv[4];
        #pragma unroll
        for (int nt = 0; nt < 4; ++nt){
          int kb8l = ks * 4 + l4;
          int col = wn * 64 + nt * 16 + l15;
          bfv[nt] = __builtin_bit_cast(bfrag, *(const uint4*)(sB + bi * 16384 + ((kb8l * 128 + col) << 4)));
        }
        #pragma unroll
        for (int mt = 0; mt < 4; ++mt)
          #pragma unroll
          for (int nt = 0; nt < 4; ++nt)
            acc[bi][mt][nt] = __builtin_amdgcn_mfma_f32_16x16x32_bf16(af[mt], bfv[nt], acc[bi][mt][nt], 0, 0, 0);
      }
    }
  }
  #pragma unroll
  for (int bi = 0; bi < NBI; ++bi){
    #pragma unroll
    for (int mt = 0; mt < 4; ++mt){
      #pragma unroll
      for (int nt = 0; nt < 4; ++nt){
        int col = bn * 128 * NBI + bi * 128 + wn * 64 + nt * 16 + l15;
        #pragma unroll
        for (int r = 0; r < 4; ++r){
          int row = bm * 128 + wm * 64 + mt * 16 + (l4 << 2) + r;
          float val = acc[bi][mt][nt][r];
          if (MODE == 0){
            int which = col >> 9, h = (col >> 6) & 7, dd = col & 63;
            u16* dst = (which == 0) ? q : (which == 1) ? kk : vv;
            int b = row >> 11, s = row & 2047;
            dst[(((size_t)(b * 8 + h) * 2048 + s) << 6) + dd] = f2bf(val);
          } else {
            out[(size_t)row * 512 + col] = val + bias[col];
          }
        }
      }
    }
  }
}

// ---------------- cluster gather -> k_proj/v_proj -> KW (conv+scale folded) ----------------
__launch_bounds__(256, 2)
__global__ void k_proj(const u16* __restrict__ kg, const u16* __restrict__ vg,
                       const float* __restrict__ EW, const float* __restrict__ FW,
                       const float* __restrict__ w1, const float* __restrict__ w3,
                       const float* __restrict__ w5, const int* __restrict__ table,
                       const int* __restrict__ counts,
                       u16* __restrict__ KW, u16* __restrict__ vp){
  int bh = blockIdx.y, b = bh >> 3, h = bh & 7;
  int ddq = blockIdx.x;
  int t = threadIdx.x;
  __shared__ float Wf[5][128];
  __shared__ float kp[64][20];
  for (int w = t; w < 640; w += 256){
    int i = w >> 7, j = w & 127;
    float a = 0.f;
    if (j >= 32 && j < 96){
      int jj = j - 32;
      a = w5[i * 64 + jj];
      if (i >= 1 && i <= 3) a += w3[(i - 1) * 64 + jj];
      if (i == 2) a += w1[jj];
      a *= (1.0f / 3.0f) * 0.125f;
    }
    Wf[i][j] = a;
  }
  int cnt = counts[b];
  const int* tab = table + (size_t)(cnt - 1) * 2048;
  int c = t >> 2, sub = t & 3;
  int dd = ddq * 16 + sub * 4;
  float ka[4] = {0.f, 0.f, 0.f, 0.f}, va[4] = {0.f, 0.f, 0.f, 0.f};
  const u16* kbase = kg + ((size_t)bh << 17) + dd;
  const u16* vbase = vg + ((size_t)bh << 17) + dd;
  const float* ewr = EW + h * 2048 + c * 32;
  const float* fwr = FW + h * 2048 + c * 32;
  #pragma unroll
  for (int l0 = 0; l0 < 32; l0 += 8){
    int4 i0 = *(const int4*)(tab + c * 32 + l0);
    int4 i1 = *(const int4*)(tab + c * 32 + l0 + 4);
    int idx[8] = {i0.x, i0.y, i0.z, i0.w, i1.x, i1.y, i1.z, i1.w};
    uint2 kq[8], vq[8];
    #pragma unroll
    for (int j = 0; j < 8; ++j){
      int ic = idx[j] < 2047 ? idx[j] : 2047;
      kq[j] = *(const uint2*)(kbase + ((size_t)ic << 6));
      vq[j] = *(const uint2*)(vbase + ((size_t)ic << 6));
    }
    #pragma unroll
    for (int j = 0; j < 8; ++j){
      float valid = (idx[j] < 2048) ? 1.0f : 0.0f;
      float we = ewr[l0 + j] * valid, wf = fwr[l0 + j] * valid;
      union { uint2 u2; u16 s[4]; } ku, vu;
      ku.u2 = kq[j]; vu.u2 = vq[j];
      #pragma unroll
      for (int m = 0; m < 4; ++m){
        ka[m] += we * bf2f(ku.s[m]);
        va[m] += wf * bf2f(vu.s[m]);
      }
    }
  }
  *(float4*)(&kp[c][sub * 4]) = make_float4(ka[0], ka[1], ka[2], ka[3]);
  {
    int pg = c >> 3, pp = c & 7;
    #pragma unroll
    for (int m = 0; m < 4; ++m)
      vp[(((size_t)bh * 8 + pg) * 64 + (dd + m)) * 8 + pp] = f2bf(va[m]);
  }
  __syncthreads();
  float acc[5][4];
  #pragma unroll
  for (int i = 0; i < 5; ++i)
    #pragma unroll
    for (int m = 0; m < 4; ++m) acc[i][m] = 0.f;
  for (int u = 0; u < 64; ++u){
    float4 k4 = *(const float4*)(&kp[u][sub * 4]);
    #pragma unroll
    for (int i = 0; i < 5; ++i){
      float w = Wf[i][u - c + 63];
      acc[i][0] += w * k4.x; acc[i][1] += w * k4.y;
      acc[i][2] += w * k4.z; acc[i][3] += w * k4.w;
    }
  }
  #pragma unroll
  for (int i = 0; i < 5; ++i){
    union { u16 s[4]; uint2 u2; } o;
    #pragma unroll
    for (int m = 0; m < 4; ++m) o.s[m] = f2bf(acc[i][m]);
    *(uint2*)(KW + (((size_t)bh * 40 + i * 8 + (dd >> 3)) * 64 + c) * 8 + (dd & 7)) = o.u2;
  }
}

// ---------------- fused conv-scores + softmax + PV, T14 async-staged Q double-buffer ------
__launch_bounds__(256, 2)
__global__ void k_attn(const u16* __restrict__ qg, const u16* __restrict__ KWg,
                       const u16* __restrict__ vpg, u16* __restrict__ concat){
  __shared__ __align__(16) char sKW[40960];
  __shared__ __align__(16) char sVP[8192];
  __shared__ __align__(16) char sQ0[8704];
  __shared__ __align__(16) char sQ1[8704];
  __shared__ __align__(16) char sW[8704];
  int bh = blockIdx.y, b = bh >> 3, h = bh & 7;
  int tid = threadIdx.x, wid = tid >> 6, lane = tid & 63;
  int l15 = lane & 15, l4 = lane >> 4;

  const char* kwb = (const char*)KWg + (size_t)bh * 40960;
  #pragma unroll
  for (int t = 0; t < 10; ++t){
    int inst = wid * 10 + t;
    gload16(kwb + ((size_t)(inst * 64 + lane) << 4), sKW + inst * 1024);
  }
  const char* vpb = (const char*)vpg + (size_t)bh * 8192;
  #pragma unroll
  for (int t = 0; t < 2; ++t){
    int inst = wid * 2 + t;
    gload16(vpb + ((size_t)(inst * 64 + lane) << 4), sVP + inst * 1024);
  }
  const u16* qb = qg + ((size_t)bh << 17);

  {
    int s0 = (blockIdx.x << 3) << 6;
    for (int ch = tid; ch < 544; ch += 256){
      int row = ch >> 3, slot = ch & 7;
      int gr = s0 - 2 + row;
      uint4 val = make_uint4(0u, 0u, 0u, 0u);
      if (gr >= 0 && gr < 2048) val = *(const uint4*)(qb + ((size_t)gr << 6) + (slot << 3));
      *(uint4*)(sQ0 + row * 128 + ((slot << 4) ^ ((row & 7) << 4))) = val;
    }
  }

  for (int st = 0; st < 8; ++st){
    char* cur = (st & 1) ? sQ1 : sQ0;
    char* nxt = (st & 1) ? sQ0 : sQ1;
    int s0 = ((blockIdx.x << 3) + st) << 6;
    __syncthreads();

    uint4 qr[3];
    if (st < 7){
      int s0n = s0 + 64;
      #pragma unroll
      for (int c2 = 0; c2 < 3; ++c2){
        int ch = tid + c2 * 256;
        qr[c2] = make_uint4(0u, 0u, 0u, 0u);
        if (ch < 544){
          int row = ch >> 3, slot = ch & 7;
          int gr = s0n - 2 + row;
          if (gr >= 0 && gr < 2048) qr[c2] = *(const uint4*)(qb + ((size_t)gr << 6) + (slot << 3));
        }
      }
    }

    f32x4 acc[4] = {};
    #pragma unroll
    for (int kb = 0; kb < 10; ++kb){
      int i = kb >> 1;
      int row = wid * 16 + l15 + i;
      int dd0b = ((kb & 1) << 6) + (l4 << 4);
      bfrag a = __builtin_bit_cast(bfrag, *(const uint4*)(cur + row * 128 + (dd0b ^ ((row & 7) << 4))));
      int kb8 = kb * 4 + l4;
      #pragma unroll
      for (int nt = 0; nt < 4; ++nt){
        bfrag bv = __builtin_bit_cast(bfrag, *(const uint4*)(sKW + ((kb8 * 64 + nt * 16 + l15) << 4)));
        acc[nt] = __builtin_amdgcn_mfma_f32_16x16x32_bf16(a, bv, acc[nt], 0, 0, 0);
      }
    }
    float wgt[4][4];
    #pragma unroll
    for (int r = 0; r < 4; ++r){
      float m = fmaxf(fmaxf(acc[0][r], acc[1][r]), fmaxf(acc[2][r], acc[3][r]));
      m = fmaxf(m, __shfl_xor(m, 1));
      m = fmaxf(m, __shfl_xor(m, 2));
      m = fmaxf(m, __shfl_xor(m, 4));
      m = fmaxf(m, __shfl_xor(m, 8));
      float e0 = __expf(acc[0][r] - m), e1 = __expf(acc[1][r] - m);
      float e2 = __expf(acc[2][r] - m), e3 = __expf(acc[3][r] - m);
      float sum = e0 + e1 + e2 + e3;
      sum += __shfl_xor(sum, 1);
      sum += __shfl_xor(sum, 2);
      sum += __shfl_xor(sum, 4);
      sum += __shfl_xor(sum, 8);
      float inv = 1.0f / sum;
      wgt[0][r] = e0 * inv; wgt[1][r] = e1 * inv; wgt[2][r] = e2 * inv; wgt[3][r] = e3 * inv;
    }
    #pragma unroll
    for (int r = 0; r < 4; ++r){
      int row = wid * 16 + (l4 << 2) + r;
      #pragma unroll
      for (int nt = 0; nt < 4; ++nt){
        int pb = (nt * 16 + l15) << 1;
        *(u16*)(sW + row * 128 + (pb ^ ((row & 7) << 4))) = f2bf(wgt[nt][r]);
      }
    }
    if (st < 7){
      #pragma unroll
      for (int c2 = 0; c2 < 3; ++c2){
        int ch = tid + c2 * 256;
        if (ch < 544){
          int row = ch >> 3, slot = ch & 7;
          *(uint4*)(nxt + row * 128 + ((slot << 4) ^ ((row & 7) << 4))) = qr[c2];
        }
      }
    }
    __syncthreads();
    f32x4 acc2[4] = {};
    #pragma unroll
    for (int ks = 0; ks < 2; ++ks){
      int row = wid * 16 + l15;
      int pb = (ks << 6) + (l4 << 4);
      bfrag a = __builtin_bit_cast(bfrag, *(const uint4*)(sW + row * 128 + (pb ^ ((row & 7) << 4))));
      int pg = ks * 4 + l4;
      #pragma unroll
      for (int nt = 0; nt < 4; ++nt){
        bfrag bv = __builtin_bit_cast(bfrag, *(const uint4*)(sVP + ((pg * 64 + nt * 16 + l15) << 4)));
        acc2[nt] = __builtin_amdgcn_mfma_f32_16x16x32_bf16(a, bv, acc2[nt], 0, 0, 0);
      }
    }
    #pragma unroll
    for (int nt = 0; nt < 4; ++nt){
      int col = (h << 6) + nt * 16 + l15;
      #pragma unroll
      for (int r = 0; r < 4; ++r){
        int s = s0 + wid * 16 + (l4 << 2) + r;
        concat[(((size_t)b << 11) + s) * 512 + col] = f2bf(acc2[nt][r]);
      }
    }
  }
}

extern "C" void kernel_launch(void* const* d_in, const int* in_sizes, int n_in,
                              void* d_out, int out_size, void* d_ws, size_t ws_size,
                              hipStream_t stream){
  const float* x   = (const float*)d_in[0];
  const void*  mask= d_in[1];
  const float* wq  = (const float*)d_in[2];
  const float* wk  = (const float*)d_in[3];
  const float* wv  = (const float*)d_in[4];
  const float* EW  = (const float*)d_in[5];
  const float* FW  = (const float*)d_in[6];
  const float* cw1 = (const float*)d_in[7];
  const float* cw3 = (const float*)d_in[8];
  const float* cw5 = (const float*)d_in[9];
  // d_in[10] conv_b: constant across softmax axis -> no-op
  const float* dw  = (const float*)d_in[11];
  const float* db  = (const float*)d_in[12];
  const int* table = (const int*)d_in[13];
  float* out = (float*)d_out;

  char* ws = (char*)d_ws;
  u16* xb     = (u16*)(ws);                    // 33,554,432 B  (reused as concat)
  u16* wb     = (u16*)(ws + 33554432);         //  1,572,864 B
  u16* dwb    = (u16*)(ws + 35127296);         //    524,288 B
  u16* q      = (u16*)(ws + 35651584);         // 33,554,432 B
  u16* kk     = (u16*)(ws + 69206016);         // 33,554,432 B
  u16* vv     = (u16*)(ws + 102760448);        // 33,554,432 B
  u16* KW     = (u16*)(ws + 136314880);        //  5,242,880 B
  u16* vp     = (u16*)(ws + 141557760);        //  1,048,576 B
  int* counts = (int*)(ws + 142606336);        //         64 B
  u16* concat = xb;

  hipLaunchKernelGGL(k_prep, dim3(2064), dim3(256), 0, stream,
                     x, mask, wq, wk, wv, dw, xb, wb, dwb, counts);
  hipLaunchKernelGGL((k_gemm<0, 2>), dim3(1536), dim3(256), 0, stream,
                     xb, wb, q, kk, vv, (float*)nullptr, (const float*)nullptr, 1536, 6);
  hipLaunchKernelGGL(k_proj, dim3(4, 128), dim3(256), 0, stream,
                     kk, vv, EW, FW, cw1, cw3, cw5, table, counts, KW, vp);
  hipLaunchKernelGGL(k_attn, dim3(4, 128), dim3(256), 0, stream, q, KW, vp, concat);
  hipLaunchKernelGGL((k_gemm<1, 1>), dim3(1024), dim3(256), 0, stream,
                     concat, dwb, (u16*)nullptr, (u16*)nullptr, (u16*)nullptr, out, db, 512, 4);
}

// Round 18
// 155.941 us; speedup vs baseline: 1.1687x; 1.1687x over previous
//
#include <hip/hip_runtime.h>
#include <hip/hip_bf16.h>

typedef unsigned short u16;
typedef unsigned int   u32;
typedef unsigned char  u8;
typedef __attribute__((ext_vector_type(8))) __bf16 bfrag;
typedef __attribute__((ext_vector_type(4))) float  f32x4;

#define DEV __device__ __forceinline__

DEV u16 f2bf(float f){
  union { float f; u32 u; } v; v.f = f;
  u32 u = v.u;
  u32 r = (u + 0x7fffu + ((u >> 16) & 1u)) >> 16;
  return (u16)r;
}
DEV float bf2f(u16 x){
  union { u32 u; float f; } v; v.u = ((u32)x) << 16;
  return v.f;
}
DEV void gload16(const void* g, void* l){
  __builtin_amdgcn_global_load_lds((const __attribute__((address_space(1))) void*)g,
                                   (__attribute__((address_space(3))) void*)l, 16, 0, 0);
}

// ============ merged prep: counts | pack wb | pack dwb | cvt x->bf16 (one dispatch) =======
__global__ void k_prep(const float* __restrict__ x, const void* __restrict__ mask,
                       const float* __restrict__ wq, const float* __restrict__ wk,
                       const float* __restrict__ wv, const float* __restrict__ dw,
                       u16* __restrict__ xb, u16* __restrict__ wb, u16* __restrict__ dwb,
                       int* __restrict__ counts){
  int gb = blockIdx.x, t = threadIdx.x;
  if (gb < 16){
    int b = gb;
    u32 h0 = *(const u32*)mask;
    int mode = (h0 == 0x3f800000u) ? 2 : (h0 == 1u) ? 1 : 0;
    int cnt = 0;
    if (mode == 0){
      const u8* p = (const u8*)mask + (size_t)b * 2048;
      for (int i = t; i < 2048; i += 256) cnt += (p[i] != 0);
    } else if (mode == 1){
      const int* p = (const int*)mask + (size_t)b * 2048;
      for (int i = t; i < 2048; i += 256) cnt += (p[i] != 0);
    } else {
      const float* p = (const float*)mask + (size_t)b * 2048;
      for (int i = t; i < 2048; i += 256) cnt += (p[i] != 0.0f);
    }
    __shared__ int red[256];
    red[t] = cnt; __syncthreads();
    for (int s = 128; s > 0; s >>= 1){ if (t < s) red[t] += red[t + s]; __syncthreads(); }
    if (t == 0){ int c = red[0]; if (c < 1) c = 1; if (c > 2048) c = 2048; counts[b] = c; }
  } else if (gb < 400){
    int c = (gb - 16) * 256 + t;
    int kb8 = c / 1536, n = c % 1536;
    const float* w = (n < 512) ? wq : (n < 1024) ? wk : wv;
    int nn = n & 511;
    union { u16 o[8]; uint4 v; } u;
    #pragma unroll
    for (int j = 0; j < 8; ++j) u.o[j] = f2bf(w[(size_t)(kb8 * 8 + j) * 512 + nn]);
    *(uint4*)(wb + (size_t)c * 8) = u.v;
  } else if (gb < 528){
    int c = (gb - 400) * 256 + t;
    int kb8 = c >> 9, nn = c & 511;
    union { u16 o[8]; uint4 v; } u;
    #pragma unroll
    for (int j = 0; j < 8; ++j) u.o[j] = f2bf(dw[(size_t)(kb8 * 8 + j) * 512 + nn]);
    *(uint4*)(dwb + (size_t)c * 8) = u.v;
  } else {
    int i = (gb - 528) * 256 + t;
    int stride = (gridDim.x - 528) * 256;
    for (; i < 2097152; i += stride){
      const float4* s = (const float4*)(x + (size_t)i * 8);
      float4 a = s[0], b = s[1];
      union { u16 o[8]; uint4 v; } u;
      u.o[0]=f2bf(a.x); u.o[1]=f2bf(a.y); u.o[2]=f2bf(a.z); u.o[3]=f2bf(a.w);
      u.o[4]=f2bf(b.x); u.o[5]=f2bf(b.y); u.o[6]=f2bf(b.z); u.o[7]=f2bf(b.w);
      *(uint4*)(xb + (size_t)i * 8) = u.v;
    }
  }
}

// ---------------- 128x128 bf16 MFMA GEMM, K=512 (R16-frozen proven body) ----------------
// + XCD-ownership swizzle; simple 2-barrier K-loop (8 structural variants all measured worse).
template<int MODE>
__launch_bounds__(256, 8)
__global__ void k_gemm(const u16* __restrict__ A, const u16* __restrict__ Bp,
                       u16* __restrict__ q, u16* __restrict__ kk, u16* __restrict__ vv,
                       float* __restrict__ out, const float* __restrict__ bias,
                       int N, int nbn){
  __shared__ __align__(16) char sA[16384];  // [128 rows][64 k] bf16, slot-XOR swizzled
  __shared__ __align__(16) char sB[16384];  // [8 kb8][128 col][8] bf16 linear
  const int tid = threadIdx.x;
  const int wid = tid >> 6, lane = tid & 63;
  int id = blockIdx.x;
  int per = gridDim.x >> 3;
  int lin = (id & 7) * per + (id >> 3);
  const int bm = lin / nbn;
  const int bn = lin - bm * nbn;
  const int wm = wid >> 1, wn = wid & 1;
  const int l15 = lane & 15, l4 = lane >> 4;

  f32x4 acc[4][4] = {};

  const char* Ab = (const char*)A;
  const char* Bb = (const char*)Bp;

  for (int kt = 0; kt < 8; ++kt){
    __syncthreads();
    #pragma unroll
    for (int t = 0; t < 4; ++t){
      int chunk = (wid * 4 + t) * 64 + lane;
      int row = chunk >> 3, slot = chunk & 7;
      const char* g = Ab + ((size_t)(bm * 128 + row) * 1024) + kt * 128 + ((slot ^ (row & 7)) << 4);
      gload16(g, sA + (wid * 4 + t) * 1024);
    }
    #pragma unroll
    for (int t = 0; t < 4; ++t){
      int idx = wid * 4 + t;
      int kb8l = idx >> 1, col = ((idx & 1) << 6) + lane;
      const char* g = Bb + ((size_t)((kt * 8 + kb8l) * N + bn * 128 + col) << 4);
      gload16(g, sB + idx * 1024);
    }
    __syncthreads();
    #pragma unroll
    for (int ks = 0; ks < 2; ++ks){
      bfrag af[4], bfv[4];
      #pragma unroll
      for (int mt = 0; mt < 4; ++mt){
        int row = wm * 64 + mt * 16 + l15;
        int slot = ks * 4 + l4;
        af[mt] = __builtin_bit_cast(bfrag, *(const uint4*)(sA + row * 128 + ((slot << 4) ^ ((row & 7) << 4))));
      }
      #pragma unroll
      for (int nt = 0; nt < 4; ++nt){
        int kb8l = ks * 4 + l4;
        int col = wn * 64 + nt * 16 + l15;
        bfv[nt] = __builtin_bit_cast(bfrag, *(const uint4*)(sB + ((kb8l * 128 + col) << 4)));
      }
      #pragma unroll
      for (int mt = 0; mt < 4; ++mt)
        #pragma unroll
        for (int nt = 0; nt < 4; ++nt)
          acc[mt][nt] = __builtin_amdgcn_mfma_f32_16x16x32_bf16(af[mt], bfv[nt], acc[mt][nt], 0, 0, 0);
    }
  }
  #pragma unroll
  for (int mt = 0; mt < 4; ++mt){
    #pragma unroll
    for (int nt = 0; nt < 4; ++nt){
      int col = bn * 128 + wn * 64 + nt * 16 + l15;
      #pragma unroll
      for (int r = 0; r < 4; ++r){
        int row = bm * 128 + wm * 64 + mt * 16 + (l4 << 2) + r;
        float val = acc[mt][nt][r];
        if (MODE == 0){
          int which = col >> 9, h = (col >> 6) & 7, dd = col & 63;
          u16* dst = (which == 0) ? q : (which == 1) ? kk : vv;
          int b = row >> 11, s = row & 2047;
          dst[(((size_t)(b * 8 + h) * 2048 + s) << 6) + dd] = f2bf(val);
        } else {
          out[(size_t)row * 512 + col] = val + bias[col];
        }
      }
    }
  }
}

// ---------------- cluster gather -> k_proj/v_proj -> KW (conv+scale folded) ----------------
// 1D grid 512, XCD-ownership: xcd = id&7 owns 16 bh; the 4 ddq-blocks of a bh are
// XCD-local -> each 128B k/v row line fetched once per XCD (was 4 XCDs x full line).
__launch_bounds__(256, 2)
__global__ void k_proj(const u16* __restrict__ kg, const u16* __restrict__ vg,
                       const float* __restrict__ EW, const float* __restrict__ FW,
                       const float* __restrict__ w1, const float* __restrict__ w3,
                       const float* __restrict__ w5, const int* __restrict__ table,
                       const int* __restrict__ counts,
                       u16* __restrict__ KW, u16* __restrict__ vp){
  int id = blockIdx.x;
  int lin = (id & 7) * 64 + (id >> 3);
  int bh = lin >> 2, ddq = lin & 3;
  int b = bh >> 3, h = bh & 7;
  int t = threadIdx.x;
  __shared__ float Wf[5][128];
  __shared__ float kp[64][20];
  for (int w = t; w < 640; w += 256){
    int i = w >> 7, j = w & 127;
    float a = 0.f;
    if (j >= 32 && j < 96){
      int jj = j - 32;
      a = w5[i * 64 + jj];
      if (i >= 1 && i <= 3) a += w3[(i - 1) * 64 + jj];
      if (i == 2) a += w1[jj];
      a *= (1.0f / 3.0f) * 0.125f;
    }
    Wf[i][j] = a;
  }
  int cnt = counts[b];
  const int* tab = table + (size_t)(cnt - 1) * 2048;
  int c = t >> 2, sub = t & 3;
  int dd = ddq * 16 + sub * 4;
  float ka[4] = {0.f, 0.f, 0.f, 0.f}, va[4] = {0.f, 0.f, 0.f, 0.f};
  const u16* kbase = kg + ((size_t)bh << 17) + dd;
  const u16* vbase = vg + ((size_t)bh << 17) + dd;
  const float* ewr = EW + h * 2048 + c * 32;
  const float* fwr = FW + h * 2048 + c * 32;
  #pragma unroll
  for (int l0 = 0; l0 < 32; l0 += 8){
    int4 i0 = *(const int4*)(tab + c * 32 + l0);
    int4 i1 = *(const int4*)(tab + c * 32 + l0 + 4);
    int idx[8] = {i0.x, i0.y, i0.z, i0.w, i1.x, i1.y, i1.z, i1.w};
    uint2 kq[8], vq[8];
    #pragma unroll
    for (int j = 0; j < 8; ++j){
      int ic = idx[j] < 2047 ? idx[j] : 2047;
      kq[j] = *(const uint2*)(kbase + ((size_t)ic << 6));
      vq[j] = *(const uint2*)(vbase + ((size_t)ic << 6));
    }
    #pragma unroll
    for (int j = 0; j < 8; ++j){
      float valid = (idx[j] < 2048) ? 1.0f : 0.0f;
      float we = ewr[l0 + j] * valid, wf = fwr[l0 + j] * valid;
      union { uint2 u2; u16 s[4]; } ku, vu;
      ku.u2 = kq[j]; vu.u2 = vq[j];
      #pragma unroll
      for (int m = 0; m < 4; ++m){
        ka[m] += we * bf2f(ku.s[m]);
        va[m] += wf * bf2f(vu.s[m]);
      }
    }
  }
  *(float4*)(&kp[c][sub * 4]) = make_float4(ka[0], ka[1], ka[2], ka[3]);
  {
    int pg = c >> 3, pp = c & 7;
    #pragma unroll
    for (int m = 0; m < 4; ++m)
      vp[(((size_t)bh * 8 + pg) * 64 + (dd + m)) * 8 + pp] = f2bf(va[m]);
  }
  __syncthreads();
  float acc[5][4];
  #pragma unroll
  for (int i = 0; i < 5; ++i)
    #pragma unroll
    for (int m = 0; m < 4; ++m) acc[i][m] = 0.f;
  for (int u = 0; u < 64; ++u){
    float4 k4 = *(const float4*)(&kp[u][sub * 4]);
    #pragma unroll
    for (int i = 0; i < 5; ++i){
      float w = Wf[i][u - c + 63];
      acc[i][0] += w * k4.x; acc[i][1] += w * k4.y;
      acc[i][2] += w * k4.z; acc[i][3] += w * k4.w;
    }
  }
  #pragma unroll
  for (int i = 0; i < 5; ++i){
    union { u16 s[4]; uint2 u2; } o;
    #pragma unroll
    for (int m = 0; m < 4; ++m) o.s[m] = f2bf(acc[i][m]);
    *(uint2*)(KW + (((size_t)bh * 40 + i * 8 + (dd >> 3)) * 64 + c) * 8 + (dd & 7)) = o.u2;
  }
}

// ---------------- fused conv-scores + softmax + PV, T14 async-staged Q double-buffer ------
// 1D grid 512, XCD-ownership: the 4 s-tile blocks sharing a bh's KW/VP panel are XCD-local.
__launch_bounds__(256, 2)
__global__ void k_attn(const u16* __restrict__ qg, const u16* __restrict__ KWg,
                       const u16* __restrict__ vpg, u16* __restrict__ concat){
  __shared__ __align__(16) char sKW[40960];
  __shared__ __align__(16) char sVP[8192];
  __shared__ __align__(16) char sQ0[8704];
  __shared__ __align__(16) char sQ1[8704];
  __shared__ __align__(16) char sW[8704];
  int id = blockIdx.x;
  int lin = (id & 7) * 64 + (id >> 3);
  int bh = lin >> 2, sx = lin & 3;
  int b = bh >> 3, h = bh & 7;
  int tid = threadIdx.x, wid = tid >> 6, lane = tid & 63;
  int l15 = lane & 15, l4 = lane >> 4;

  const char* kwb = (const char*)KWg + (size_t)bh * 40960;
  #pragma unroll
  for (int t = 0; t < 10; ++t){
    int inst = wid * 10 + t;
    gload16(kwb + ((size_t)(inst * 64 + lane) << 4), sKW + inst * 1024);
  }
  const char* vpb = (const char*)vpg + (size_t)bh * 8192;
  #pragma unroll
  for (int t = 0; t < 2; ++t){
    int inst = wid * 2 + t;
    gload16(vpb + ((size_t)(inst * 64 + lane) << 4), sVP + inst * 1024);
  }
  const u16* qb = qg + ((size_t)bh << 17);

  {
    int s0 = (sx << 3) << 6;
    for (int ch = tid; ch < 544; ch += 256){
      int row = ch >> 3, slot = ch & 7;
      int gr = s0 - 2 + row;
      uint4 val = make_uint4(0u, 0u, 0u, 0u);
      if (gr >= 0 && gr < 2048) val = *(const uint4*)(qb + ((size_t)gr << 6) + (slot << 3));
      *(uint4*)(sQ0 + row * 128 + ((slot << 4) ^ ((row & 7) << 4))) = val;
    }
  }

  for (int st = 0; st < 8; ++st){
    char* cur = (st & 1) ? sQ1 : sQ0;
    char* nxt = (st & 1) ? sQ0 : sQ1;
    int s0 = ((sx << 3) + st) << 6;
    __syncthreads();

    uint4 qr[3];
    if (st < 7){
      int s0n = s0 + 64;
      #pragma unroll
      for (int c2 = 0; c2 < 3; ++c2){
        int ch = tid + c2 * 256;
        qr[c2] = make_uint4(0u, 0u, 0u, 0u);
        if (ch < 544){
          int row = ch >> 3, slot = ch & 7;
          int gr = s0n - 2 + row;
          if (gr >= 0 && gr < 2048) qr[c2] = *(const uint4*)(qb + ((size_t)gr << 6) + (slot << 3));
        }
      }
    }

    f32x4 acc[4] = {};
    #pragma unroll
    for (int kb = 0; kb < 10; ++kb){
      int i = kb >> 1;
      int row = wid * 16 + l15 + i;
      int dd0b = ((kb & 1) << 6) + (l4 << 4);
      bfrag a = __builtin_bit_cast(bfrag, *(const uint4*)(cur + row * 128 + (dd0b ^ ((row & 7) << 4))));
      int kb8 = kb * 4 + l4;
      #pragma unroll
      for (int nt = 0; nt < 4; ++nt){
        bfrag bv = __builtin_bit_cast(bfrag, *(const uint4*)(sKW + ((kb8 * 64 + nt * 16 + l15) << 4)));
        acc[nt] = __builtin_amdgcn_mfma_f32_16x16x32_bf16(a, bv, acc[nt], 0, 0, 0);
      }
    }
    float wgt[4][4];
    #pragma unroll
    for (int r = 0; r < 4; ++r){
      float m = fmaxf(fmaxf(acc[0][r], acc[1][r]), fmaxf(acc[2][r], acc[3][r]));
      m = fmaxf(m, __shfl_xor(m, 1));
      m = fmaxf(m, __shfl_xor(m, 2));
      m = fmaxf(m, __shfl_xor(m, 4));
      m = fmaxf(m, __shfl_xor(m, 8));
      float e0 = __expf(acc[0][r] - m), e1 = __expf(acc[1][r] - m);
      float e2 = __expf(acc[2][r] - m), e3 = __expf(acc[3][r] - m);
      float sum = e0 + e1 + e2 + e3;
      sum += __shfl_xor(sum, 1);
      sum += __shfl_xor(sum, 2);
      sum += __shfl_xor(sum, 4);
      sum += __shfl_xor(sum, 8);
      float inv = 1.0f / sum;
      wgt[0][r] = e0 * inv; wgt[1][r] = e1 * inv; wgt[2][r] = e2 * inv; wgt[3][r] = e3 * inv;
    }
    #pragma unroll
    for (int r = 0; r < 4; ++r){
      int row = wid * 16 + (l4 << 2) + r;
      #pragma unroll
      for (int nt = 0; nt < 4; ++nt){
        int pb = (nt * 16 + l15) << 1;
        *(u16*)(sW + row * 128 + (pb ^ ((row & 7) << 4))) = f2bf(wgt[nt][r]);
      }
    }
    if (st < 7){
      #pragma unroll
      for (int c2 = 0; c2 < 3; ++c2){
        int ch = tid + c2 * 256;
        if (ch < 544){
          int row = ch >> 3, slot = ch & 7;
          *(uint4*)(nxt + row * 128 + ((slot << 4) ^ ((row & 7) << 4))) = qr[c2];
        }
      }
    }
    __syncthreads();
    f32x4 acc2[4] = {};
    #pragma unroll
    for (int ks = 0; ks < 2; ++ks){
      int row = wid * 16 + l15;
      int pb = (ks << 6) + (l4 << 4);
      bfrag a = __builtin_bit_cast(bfrag, *(const uint4*)(sW + row * 128 + (pb ^ ((row & 7) << 4))));
      int pg = ks * 4 + l4;
      #pragma unroll
      for (int nt = 0; nt < 4; ++nt){
        bfrag bv = __builtin_bit_cast(bfrag, *(const uint4*)(sVP + ((pg * 64 + nt * 16 + l15) << 4)));
        acc2[nt] = __builtin_amdgcn_mfma_f32_16x16x32_bf16(a, bv, acc2[nt], 0, 0, 0);
      }
    }
    #pragma unroll
    for (int nt = 0; nt < 4; ++nt){
      int col = (h << 6) + nt * 16 + l15;
      #pragma unroll
      for (int r = 0; r < 4; ++r){
        int s = s0 + wid * 16 + (l4 << 2) + r;
        concat[(((size_t)b << 11) + s) * 512 + col] = f2bf(acc2[nt][r]);
      }
    }
  }
}

extern "C" void kernel_launch(void* const* d_in, const int* in_sizes, int n_in,
                              void* d_out, int out_size, void* d_ws, size_t ws_size,
                              hipStream_t stream){
  const float* x   = (const float*)d_in[0];
  const void*  mask= d_in[1];
  const float* wq  = (const float*)d_in[2];
  const float* wk  = (const float*)d_in[3];
  const float* wv  = (const float*)d_in[4];
  const float* EW  = (const float*)d_in[5];
  const float* FW  = (const float*)d_in[6];
  const float* cw1 = (const float*)d_in[7];
  const float* cw3 = (const float*)d_in[8];
  const float* cw5 = (const float*)d_in[9];
  // d_in[10] conv_b: constant across softmax axis -> no-op
  const float* dw  = (const float*)d_in[11];
  const float* db  = (const float*)d_in[12];
  const int* table = (const int*)d_in[13];
  float* out = (float*)d_out;

  char* ws = (char*)d_ws;
  u16* xb     = (u16*)(ws);                    // 33,554,432 B  (reused as concat)
  u16* wb     = (u16*)(ws + 33554432);         //  1,572,864 B
  u16* dwb    = (u16*)(ws + 35127296);         //    524,288 B
  u16* q      = (u16*)(ws + 35651584);         // 33,554,432 B
  u16* kk     = (u16*)(ws + 69206016);         // 33,554,432 B
  u16* vv     = (u16*)(ws + 102760448);        // 33,554,432 B
  u16* KW     = (u16*)(ws + 136314880);        //  5,242,880 B
  u16* vp     = (u16*)(ws + 141557760);        //  1,048,576 B
  int* counts = (int*)(ws + 142606336);        //         64 B
  u16* concat = xb;

  hipLaunchKernelGGL(k_prep, dim3(2064), dim3(256), 0, stream,
                     x, mask, wq, wk, wv, dw, xb, wb, dwb, counts);
  hipLaunchKernelGGL((k_gemm<0>), dim3(3072), dim3(256), 0, stream,
                     xb, wb, q, kk, vv, (float*)nullptr, (const float*)nullptr, 1536, 12);
  hipLaunchKernelGGL(k_proj, dim3(512), dim3(256), 0, stream,
                     kk, vv, EW, FW, cw1, cw3, cw5, table, counts, KW, vp);
  hipLaunchKernelGGL(k_attn, dim3(512), dim3(256), 0, stream, q, KW, vp, concat);
  hipLaunchKernelGGL((k_gemm<1>), dim3(1024), dim3(256), 0, stream,
                     concat, dwb, (u16*)nullptr, (u16*)nullptr, (u16*)nullptr, out, db, 512, 4);
}